// Round 9
// baseline (52.212 us; speedup 1.0000x reference)
//
#include <hip/hip_runtime.h>
#include <hip/hip_bf16.h>

typedef short bf16x8 __attribute__((ext_vector_type(8)));
typedef float f32x4  __attribute__((ext_vector_type(4)));

#define NB 64
#define NN 512
#define DD 128

// RNE float -> bf16 (finite inputs)
__device__ __forceinline__ unsigned short f2bf(float f) {
    unsigned int u = __float_as_uint(f);
    unsigned int r = (u + 0x7FFFu + ((u >> 16) & 1u)) >> 16;
    return (unsigned short)r;
}

// Kernel 1: per-row L2 normalize, write bf16 fn into workspace.
// XCD-pinned with the same decode as the adj kernel.
__global__ __launch_bounds__(256) void ASG_norm_kernel(
    const float* __restrict__ fea, unsigned int* __restrict__ fn)
{
    const int id   = blockIdx.x;        // 0..2047
    const int xcd  = id & 7;
    const int q    = id >> 3;           // 0..255
    const int b    = xcd + 8 * (q >> 5);
    const int t    = q & 31;            // 32 blocks/batch, 16 rows each
    const int wid  = threadIdx.x >> 6;
    const int lane = threadIdx.x & 63;
    const int row0 = b * NN + t * 16 + wid * 4;
    const float2* src = reinterpret_cast<const float2*>(fea);

    float2 v[4];
    float  s[4];
#pragma unroll
    for (int rr = 0; rr < 4; ++rr) {
        v[rr] = src[(size_t)(row0 + rr) * (DD / 2) + lane];
        s[rr] = v[rr].x * v[rr].x + v[rr].y * v[rr].y;
    }
#pragma unroll
    for (int o = 32; o; o >>= 1) {
#pragma unroll
        for (int rr = 0; rr < 4; ++rr) s[rr] += __shfl_xor(s[rr], o);
    }
#pragma unroll
    for (int rr = 0; rr < 4; ++rr) {
        const float scale = 1.0f / fmaxf(sqrtf(s[rr]), 1e-8f);
        const unsigned short a = f2bf(v[rr].x * scale);
        const unsigned short bb = f2bf(v[rr].y * scale);
        fn[(size_t)(row0 + rr) * (DD / 2) + lane] =
            (unsigned int)a | ((unsigned int)bb << 16);
    }
}

// Kernel 2: block = 64 rows x 128 cols; wave = 16 rows x 128 cols.
// MFMA n-loop scatters into wave-private LDS; then an A-phase of 8
// ascending 2-row x 512B-contiguous stores, then a separate S-phase
// (dist recomputed) — long linear write runs, streams separated.
__global__ __launch_bounds__(256, 4) void ASG_adj_kernel(
    const unsigned short* __restrict__ fn, const float* __restrict__ coord,
    float* __restrict__ out)
{
    const int id  = blockIdx.x;        // 0..2047
    const int xcd = id & 7;
    const int q   = id >> 3;           // 0..255
    const int b   = xcd + 8 * (q >> 5);
    const int t   = q & 31;
    const int bi  = t >> 2;            // 64-row stripe 0..7
    const int bj  = t & 3;             // 128-col stripe 0..3

    const int tid = threadIdx.x;
    const int wid = tid >> 6, lane = tid & 63;
    const int lo = lane & 15, hi = lane >> 4;
    const int row0 = bi * 64 + wid * 16;   // wave's 16 rows
    const int col0 = bj * 128;             // block's 128 cols (all waves)

    __shared__ float2 crow[64];
    __shared__ float2 ccol[128];
    __shared__ float  xpose[4][16 * 132];  // wave-private, pad 132

    const float2* cb = reinterpret_cast<const float2*>(coord) + (size_t)b * NN;
    if (tid < 64)       crow[tid] = cb[bi * 64 + tid];
    else if (tid < 192) ccol[tid - 64] = cb[col0 + (tid - 64)];
    __syncthreads();

    const unsigned short* fb = fn + (size_t)b * NN * DD;
    const int lk = hi * 8;             // k start (bf16 elements)

    // A fragments: wave's 16 rows, loaded once (4 dwordx4)
    bf16x8 afrag[4];
    {
        const unsigned short* p = fb + (size_t)(row0 + lo) * DD + lk;
#pragma unroll
        for (int kk = 0; kk < 4; ++kk)
            afrag[kk] = *reinterpret_cast<const bf16x8*>(p + kk * 32);
    }

    float* xp = xpose[wid];

#define LOADB(DST, N)                                                         \
    {                                                                         \
        const unsigned short* p =                                             \
            fb + (size_t)(col0 + (N) * 16 + lo) * DD + lk;                    \
        _Pragma("unroll")                                                     \
        for (int kk = 0; kk < 4; ++kk)                                        \
            DST[kk] = *reinterpret_cast<const bf16x8*>(p + kk * 32);          \
    }

#define STEPN(N, CUR, NXT, PREF)                                              \
    {                                                                         \
        if (PREF) LOADB(NXT, (N) + 1);                                        \
        f32x4 acc = (f32x4){0.f, 0.f, 0.f, 0.f};                              \
        _Pragma("unroll")                                                     \
        for (int kk = 0; kk < 4; ++kk)                                        \
            acc = __builtin_amdgcn_mfma_f32_16x16x32_bf16(                    \
                afrag[kk], CUR[kk], acc, 0, 0, 0);                            \
        _Pragma("unroll")                                                     \
        for (int r = 0; r < 4; ++r)                                           \
            xp[(hi * 4 + r) * 132 + (N) * 16 + lo] = acc[r];                  \
    }

    bf16x8 bf0[4], bf1[4];
    LOADB(bf0, 0);
    STEPN(0, bf0, bf1, 1);
    STEPN(1, bf1, bf0, 1);
    STEPN(2, bf0, bf1, 1);
    STEPN(3, bf1, bf0, 1);
    STEPN(4, bf0, bf1, 1);
    STEPN(5, bf1, bf0, 1);
    STEPN(6, bf0, bf1, 1);
    STEPN(7, bf1, bf0, 0);
#undef STEPN
#undef LOADB

    // Per-lane fixed output columns: jb..jb+3 (512B run per 32 lanes)
    const int rsel = lane >> 5;            // 0/1: which of the 2 rows
    const int csel = (lane & 31) * 4;      // col offset within 128
    const int jb = col0 + csel;
    float2 cj[4];
#pragma unroll
    for (int c = 0; c < 4; ++c) cj[c] = ccol[csel + c];

    float* outA = out + (size_t)b * NN * NN;
    float* outS = out + (size_t)NB * NN * NN + (size_t)b * NN * NN;

    // A-phase: 8 ascending stores, 2 rows x 512B each
#pragma unroll
    for (int p = 0; p < 8; ++p) {
        const int lr = p * 2 + rsel;       // local row 0..15
        const f32x4 cv = *reinterpret_cast<const f32x4*>(&xp[lr * 132 + csel]);
        const int i = row0 + lr;
        const float2 ci = crow[wid * 16 + lr];
        f32x4 av;
#pragma unroll
        for (int c = 0; c < 4; ++c) {
            // bit-exact numpy chain: mul, mul, add, sqrt (no FMA)
            const float dx = ci.x - cj[c].x;
            const float dy = ci.y - cj[c].y;
            const float d2 = __fadd_rn(__fmul_rn(dx, dx), __fmul_rn(dy, dy));
            const float dist = __fsqrt_rn(d2);
            const bool diag = (i == jb + c);
            av[c] = diag ? 0.0f : cv[c] * __expf(-dist);
        }
        *reinterpret_cast<f32x4*>(outA + (size_t)i * NN + jb) = av;
    }

    // S-phase: dist recomputed (cheap), separate ascending stream
#pragma unroll
    for (int p = 0; p < 8; ++p) {
        const int lr = p * 2 + rsel;
        const int i = row0 + lr;
        const float2 ci = crow[wid * 16 + lr];
        f32x4 sv;
#pragma unroll
        for (int c = 0; c < 4; ++c) {
            const float dx = ci.x - cj[c].x;
            const float dy = ci.y - cj[c].y;
            const float d2 = __fadd_rn(__fmul_rn(dx, dx), __fmul_rn(dy, dy));
            const float dist = __fsqrt_rn(d2);
            const bool diag = (i == jb + c);
            sv[c] = (!diag && dist < 1.0f) ? 1.0f : 0.0f;
        }
        *reinterpret_cast<f32x4*>(outS + (size_t)i * NN + jb) = sv;
    }
}

extern "C" void kernel_launch(void* const* d_in, const int* in_sizes, int n_in,
                              void* d_out, int out_size, void* d_ws, size_t ws_size,
                              hipStream_t stream) {
    const float* fea   = (const float*)d_in[0];   // [64,512,128] f32
    const float* coord = (const float*)d_in[1];   // [64,512,2]   f32
    float* out = (float*)d_out;                   // [2,64,512,512] f32
    unsigned int* fn_ws = (unsigned int*)d_ws;    // bf16 fn, 8 MB

    ASG_norm_kernel<<<dim3(2048), 256, 0, stream>>>(fea, fn_ws);
    ASG_adj_kernel<<<dim3(2048), 256, 0, stream>>>(
        (const unsigned short*)fn_ws, coord, out);
}